// Round 1
// baseline (127.311 us; speedup 1.0000x reference)
//
#include <hip/hip_runtime.h>
#include <hip/hip_bf16.h>
#include <cstdint>

#define MUL   128
#define ROWS  32
#define NW    8
#define TPB   (NW * 64)

typedef __attribute__((ext_vector_type(8))) short  short8;
typedef __attribute__((ext_vector_type(8))) __bf16 bf16x8;
typedef __attribute__((ext_vector_type(4))) float  f32x4;
typedef __attribute__((ext_vector_type(4))) short  short4v;

// f32 -> bf16 round-to-nearest-even (bit trick; NaN irrelevant here)
__device__ __forceinline__ short f2bf(float f) {
    union { float f; unsigned int u; } v; v.f = f;
    unsigned int u = v.u;
    u += 0x7fffu + ((u >> 16) & 1u);
    return (short)(u >> 16);
}

__device__ __forceinline__ float silu_f(float x) {
    return x / (1.0f + __expf(-x));
}

// ---- LDS geometry: five [32][128] bf16 buffers, 256 B row stride, XOR-swizzled
#define RSB     256
#define OFF_X0  0
#define OFF_X1  8192     /* + i*8192, i=0..2 */
#define OFF_H0  32768
#define OFF_H1  40960    /* + i*8192 */
#define SMEM_BYTES 65536

__device__ __forceinline__ int swz(int row, int byteInRow) {
    return row * RSB + (byteInRow ^ ((row & 7) << 4));
}

// A-fragment (16x32 bf16) from swizzled LDS tile: row = lane&15, k = 8*(lane>>4)+j
__device__ __forceinline__ short8 lds_afrag(const char* sm, int off, int r0, int ks, int lane) {
    int row = r0 + (lane & 15);
    int bi  = ks * 64 + ((lane >> 4) << 4);
    return *(const short8*)(sm + off + swz(row, bi));
}

// B-fragment (32x16) loaded directly from f32 row-major W[k][ldn], converted to bf16.
// lane: col = c0 + (lane&15), k = ks*32 + 8*(lane>>4) + j. Fully coalesced (16 x 64B).
__device__ __forceinline__ short8 bfrag_f32(const float* __restrict__ W, int ldn,
                                            int c0, int ks, int lane) {
    const float* p = W + (size_t)(ks * 32 + ((lane >> 4) << 3)) * ldn + (c0 + (lane & 15));
    short8 r;
#pragma unroll
    for (int j = 0; j < 8; ++j) r[j] = f2bf(p[(size_t)j * ldn]);
    return r;
}

__device__ __forceinline__ f32x4 mfma16(short8 a, short8 b, f32x4 c) {
    return __builtin_amdgcn_mfma_f32_16x16x32_bf16(
        __builtin_bit_cast(bf16x8, a), __builtin_bit_cast(bf16x8, b), c, 0, 0, 0);
}

__global__ __launch_bounds__(TPB, 4) void gnlr_fused_kernel(
    const float* __restrict__ x,
    const float* __restrict__ w1s, const float* __restrict__ w1v,
    const float* __restrict__ w2s, const float* __restrict__ w2v,
    float* __restrict__ out, int n)
{
    __shared__ alignas(16) char sm[SMEM_BYTES];

    const int tid   = threadIdx.x;
    const int lane  = tid & 63;
    const int w     = tid >> 6;          // wave id 0..7
    const int row0g = blockIdx.x * ROWS;
    const float INV = 0.08838834764831845f;  // 1/sqrt(128)

    // ---------------- stage x -> LDS (bf16, swizzled) ----------------
    // X0 region: rows x 128 cols, as 1024 float4 groups
#pragma unroll
    for (int it = 0; it < 2; ++it) {
        int idx = tid + it * TPB;                 // 0..1023
        int row = idx >> 5;
        int c4  = (idx & 31) << 2;                // col (multiple of 4)
        int rg  = row0g + row; if (rg >= n) rg = n - 1;
        float4 f = *(const float4*)(x + (size_t)rg * 512 + c4);
        short4v pk;
        pk.x = f2bf(f.x); pk.y = f2bf(f.y); pk.z = f2bf(f.z); pk.w = f2bf(f.w);
        *(short4v*)(sm + OFF_X0 + swz(row, c4 * 2)) = pk;
    }
    // X1 region: x[n][128 + 3u + i] -> X1[i][n][u]; 12 floats (3 float4) = 4 u's x 3 i's
#pragma unroll
    for (int it = 0; it < 2; ++it) {
        int idx = tid + it * TPB;                 // 0..1023
        int row = idx >> 5;
        int grp = idx & 31;                       // u-group: u = grp*4 .. grp*4+3
        int rg  = row0g + row; if (rg >= n) rg = n - 1;
        const float* p = x + (size_t)rg * 512 + 128 + grp * 12;
        float4 fa = *(const float4*)(p);
        float4 fb = *(const float4*)(p + 4);
        float4 fc = *(const float4*)(p + 8);
        float f[12] = { fa.x, fa.y, fa.z, fa.w, fb.x, fb.y, fb.z, fb.w, fc.x, fc.y, fc.z, fc.w };
#pragma unroll
        for (int i = 0; i < 3; ++i) {
            short4v pk;
            pk.x = f2bf(f[i]); pk.y = f2bf(f[3 + i]); pk.z = f2bf(f[6 + i]); pk.w = f2bf(f[9 + i]);
            *(short4v*)(sm + OFF_X1 + i * 8192 + swz(row, grp * 8)) = pk;
        }
    }
    __syncthreads();

    const f32x4 z = { 0.f, 0.f, 0.f, 0.f };
    const int c0 = w * 16;                        // this wave's col-tile base (u-space)

    // ---------------- phase 1: s = x0 @ w1_s; h0 -> LDS, g -> regs ----------------
    short8 bs0[4], bs1[4];
#pragma unroll
    for (int ks = 0; ks < 4; ++ks) {
        bs0[ks] = bfrag_f32(w1s, 256, c0, ks, lane);        // h0 columns
        bs1[ks] = bfrag_f32(w1s, 256, 128 + c0, ks, lane);  // g columns
    }
    float g_reg[2][4];
#pragma unroll
    for (int rt = 0; rt < 2; ++rt) {
        f32x4 a0 = z, a1 = z;
#pragma unroll
        for (int ks = 0; ks < 4; ++ks) {
            short8 a = lds_afrag(sm, OFF_X0, rt * 16, ks, lane);
            a0 = mfma16(a, bs0[ks], a0);
            a1 = mfma16(a, bs1[ks], a1);
        }
#pragma unroll
        for (int j = 0; j < 4; ++j) {
            int row = rt * 16 + ((lane >> 4) << 2) + j;
            int col = c0 + (lane & 15);
            float h0 = silu_f(a0[j] * INV);
            *(short*)(sm + OFF_H0 + swz(row, col * 2)) = f2bf(h0);
            g_reg[rt][j] = silu_f(a1[j] * INV);
        }
    }

    // ---------------- phase 2: v_i = x1_i @ w1_v; h1_i = v_i * g -> LDS ----------------
    short8 bv[4];
#pragma unroll
    for (int ks = 0; ks < 4; ++ks) bv[ks] = bfrag_f32(w1v, 128, c0, ks, lane);
#pragma unroll
    for (int i = 0; i < 3; ++i) {
#pragma unroll
        for (int rt = 0; rt < 2; ++rt) {
            f32x4 acc = z;
#pragma unroll
            for (int ks = 0; ks < 4; ++ks) {
                short8 a = lds_afrag(sm, OFF_X1 + i * 8192, rt * 16, ks, lane);
                acc = mfma16(a, bv[ks], acc);
            }
#pragma unroll
            for (int j = 0; j < 4; ++j) {
                int row = rt * 16 + ((lane >> 4) << 2) + j;
                int col = c0 + (lane & 15);
                float h1 = acc[j] * INV * g_reg[rt][j];
                *(short*)(sm + OFF_H1 + i * 8192 + swz(row, col * 2)) = f2bf(h1);
            }
        }
    }
    __syncthreads();

    // ---------------- phase 3: y0 = h0 @ w2_s, y1_i = h1_i @ w2_v -> global ----------------
    short8 b2s[4], b2v[4];
#pragma unroll
    for (int ks = 0; ks < 4; ++ks) {
        b2s[ks] = bfrag_f32(w2s, 128, c0, ks, lane);
        b2v[ks] = bfrag_f32(w2v, 128, c0, ks, lane);
    }
    // y0: out[:, c0 + (lane&15)]
#pragma unroll
    for (int rt = 0; rt < 2; ++rt) {
        f32x4 acc = z;
#pragma unroll
        for (int ks = 0; ks < 4; ++ks)
            acc = mfma16(lds_afrag(sm, OFF_H0, rt * 16, ks, lane), b2s[ks], acc);
#pragma unroll
        for (int j = 0; j < 4; ++j) {
            int row = rt * 16 + ((lane >> 4) << 2) + j;
            int rg  = row0g + row;
            if (rg < n) out[(size_t)rg * 512 + c0 + (lane & 15)] = acc[j] * INV;
        }
    }
    // y1_i: out[:, 128 + 3*u + i], u = c0 + (lane&15)
#pragma unroll
    for (int i = 0; i < 3; ++i) {
#pragma unroll
        for (int rt = 0; rt < 2; ++rt) {
            f32x4 acc = z;
#pragma unroll
            for (int ks = 0; ks < 4; ++ks)
                acc = mfma16(lds_afrag(sm, OFF_H1 + i * 8192, rt * 16, ks, lane), b2v[ks], acc);
#pragma unroll
            for (int j = 0; j < 4; ++j) {
                int row = rt * 16 + ((lane >> 4) << 2) + j;
                int rg  = row0g + row;
                if (rg < n) out[(size_t)rg * 512 + 128 + 3 * (c0 + (lane & 15)) + i] = acc[j] * INV;
            }
        }
    }
}

extern "C" void kernel_launch(void* const* d_in, const int* in_sizes, int n_in,
                              void* d_out, int out_size, void* d_ws, size_t ws_size,
                              hipStream_t stream) {
    const float* x   = (const float*)d_in[0];
    const float* w1s = (const float*)d_in[1];
    const float* w1v = (const float*)d_in[2];
    const float* w2s = (const float*)d_in[3];
    const float* w2v = (const float*)d_in[4];
    float* out = (float*)d_out;
    const int n = in_sizes[0] / (4 * MUL);
    const int grid = (n + ROWS - 1) / ROWS;
    gnlr_fused_kernel<<<grid, TPB, 0, stream>>>(x, w1s, w1v, w2s, w2v, out, n);
}

// Round 2
// 107.487 us; speedup vs baseline: 1.1844x; 1.1844x over previous
//
#include <hip/hip_runtime.h>
#include <cstdint>

#define TPB  512
#define ROWS 32

typedef __attribute__((ext_vector_type(8))) short  short8;
typedef __attribute__((ext_vector_type(8))) __bf16 bf16x8;
typedef __attribute__((ext_vector_type(4))) float  f32x4;
typedef __attribute__((ext_vector_type(4))) short  short4v;

__device__ __forceinline__ short f2bf(float f) {
    union { float f; unsigned int u; } v; v.f = f;
    unsigned int u = v.u;
    u += 0x7fffu + ((u >> 16) & 1u);
    return (short)(u >> 16);
}
__device__ __forceinline__ float silu_f(float x) { return x / (1.0f + __expf(-x)); }

// ---- LDS: 256B row stride, XOR swizzle; regions (40KB total):
// X0 @0 (8K), X1_i @8K+8K*i (24K), H0 @32K (8K); H1_i overlays @ i*8K (X0/X1_0/X1_1)
#define RSB 256
#define OFF_X0 0
#define OFF_X1 8192
#define OFF_H0 32768
#define SMEM_BYTES 40960

__device__ __forceinline__ int swz(int row, int b) { return row * RSB + (b ^ ((row & 7) << 4)); }

// B-fragment (X/H operand) from swizzled LDS: n-row = lane&15, k = ks*32 + 8*(lane>>4)+j
__device__ __forceinline__ short8 lds_bfrag(const char* sm, int off, int r0, int ks, int lane) {
    int row = r0 + (lane & 15);
    int bi  = ks * 64 + ((lane >> 4) << 4);
    return *(const short8*)(sm + off + swz(row, bi));
}

// A-fragment (weight operand): lane holds W[k = ks*32+8*(lane>>4)+j][u = tile*16 + (lane&15)]
template<bool PACKED>
__device__ __forceinline__ short8 wfrag(const short8* pw, const float* W, int ldn,
                                        int gtile, int ltile, int ks, int lane) {
    if constexpr (PACKED) {
        return pw[(gtile * 4 + ks) * 64 + lane];
    } else {
        const float* p = W + (size_t)(ks * 32 + ((lane >> 4) << 3)) * ldn + ltile * 16 + (lane & 15);
        short8 r;
#pragma unroll
        for (int j = 0; j < 8; ++j) r[j] = f2bf(p[(size_t)j * ldn]);
        return r;
    }
}

__device__ __forceinline__ f32x4 mfma16(short8 a, short8 b, f32x4 c) {
    return __builtin_amdgcn_mfma_f32_16x16x32_bf16(
        __builtin_bit_cast(bf16x8, a), __builtin_bit_cast(bf16x8, b), c, 0, 0, 0);
}

// ---- prep: pack all weights to bf16 fragment layout in d_ws.
// Global tiles: w1s 0..15 (cols 0..255), w1v 16..23, w2s 24..31, w2v 32..39.
__global__ void prep_pack(const float* __restrict__ w1s, const float* __restrict__ w1v,
                          const float* __restrict__ w2s, const float* __restrict__ w2v,
                          short8* __restrict__ pk) {
    int b = blockIdx.x;          // 0..39 = global tile
    int t = threadIdx.x;         // 0..255
    int ks = t >> 6, lane = t & 63;
    const float* W; int ldn, lt;
    if (b < 16)      { W = w1s; ldn = 256; lt = b; }
    else if (b < 24) { W = w1v; ldn = 128; lt = b - 16; }
    else if (b < 32) { W = w2s; ldn = 128; lt = b - 24; }
    else             { W = w2v; ldn = 128; lt = b - 32; }
    const float* p = W + (size_t)(ks * 32 + ((lane >> 4) << 3)) * ldn + lt * 16 + (lane & 15);
    short8 r;
#pragma unroll
    for (int j = 0; j < 8; ++j) r[j] = f2bf(p[(size_t)j * ldn]);
    pk[(b * 4 + ks) * 64 + lane] = r;
}

template<bool PACKED>
__global__ __launch_bounds__(TPB, 8) void gnlr_fused_kernel(
    const float* __restrict__ x,
    const float* __restrict__ w1s, const float* __restrict__ w1v,
    const float* __restrict__ w2s, const float* __restrict__ w2v,
    const short8* __restrict__ pw,
    float* __restrict__ out, int n)
{
    __shared__ alignas(16) char sm[SMEM_BYTES];

    const int tid   = threadIdx.x;
    const int lane  = tid & 63;
    const int w     = tid >> 6;              // wave 0..7; owns u-tile c0 = 16w
    const int row0g = blockIdx.x * ROWS;
    const int c0    = w * 16;
    const float INV = 0.08838834764831845f;  // 1/sqrt(128)
    const f32x4 z = { 0.f, 0.f, 0.f, 0.f };

    // ---------------- stage x -> LDS (bf16, swizzled) ----------------
#pragma unroll
    for (int it = 0; it < 2; ++it) {
        int idx = tid + it * TPB;            // 0..1023
        int row = idx >> 5;
        int c4  = (idx & 31) << 2;
        int rg  = row0g + row; if (rg >= n) rg = n - 1;
        float4 f = *(const float4*)(x + (size_t)rg * 512 + c4);
        short4v pkv;
        pkv.x = f2bf(f.x); pkv.y = f2bf(f.y); pkv.z = f2bf(f.z); pkv.w = f2bf(f.w);
        *(short4v*)(sm + OFF_X0 + swz(row, c4 * 2)) = pkv;
    }
#pragma unroll
    for (int it = 0; it < 2; ++it) {
        int idx = tid + it * TPB;
        int row = idx >> 5;
        int grp = idx & 31;                  // u = grp*4 .. grp*4+3
        int rg  = row0g + row; if (rg >= n) rg = n - 1;
        const float* p = x + (size_t)rg * 512 + 128 + grp * 12;
        float4 fa = *(const float4*)(p);
        float4 fb = *(const float4*)(p + 4);
        float4 fc = *(const float4*)(p + 8);
        float f[12] = { fa.x, fa.y, fa.z, fa.w, fb.x, fb.y, fb.z, fb.w, fc.x, fc.y, fc.z, fc.w };
#pragma unroll
        for (int i = 0; i < 3; ++i) {
            short4v pkv;
            pkv.x = f2bf(f[i]); pkv.y = f2bf(f[3 + i]); pkv.z = f2bf(f[6 + i]); pkv.w = f2bf(f[9 + i]);
            *(short4v*)(sm + OFF_X1 + i * 8192 + swz(row, grp * 8)) = pkv;
        }
    }
    __syncthreads();

    // ---------------- phase 1: s = x0 @ w1_s (transposed MFMA) ----------------
    // D: col(lane&15) = n-row, row((lane>>4)*4+j) = u  -> lane holds 4 consecutive u
    float g_reg[2][4];
    {
        short8 bs[4];
#pragma unroll
        for (int ks = 0; ks < 4; ++ks) bs[ks] = wfrag<PACKED>(pw, w1s, 256, w, w, ks, lane);
#pragma unroll
        for (int rt = 0; rt < 2; ++rt) {
            f32x4 acc = z;
#pragma unroll
            for (int ks = 0; ks < 4; ++ks)
                acc = mfma16(bs[ks], lds_bfrag(sm, OFF_X0, rt * 16, ks, lane), acc);
            short4v pkv;
#pragma unroll
            for (int j = 0; j < 4; ++j) pkv[j] = f2bf(silu_f(acc[j] * INV));
            int row = rt * 16 + (lane & 15);
            *(short4v*)(sm + OFF_H0 + swz(row, 2 * (c0 + ((lane >> 4) << 2)))) = pkv;
        }
        // gate half: cols 128+c0 -> global tile 8+w
#pragma unroll
        for (int ks = 0; ks < 4; ++ks) bs[ks] = wfrag<PACKED>(pw, w1s, 256, 8 + w, 8 + w, ks, lane);
#pragma unroll
        for (int rt = 0; rt < 2; ++rt) {
            f32x4 acc = z;
#pragma unroll
            for (int ks = 0; ks < 4; ++ks)
                acc = mfma16(bs[ks], lds_bfrag(sm, OFF_X0, rt * 16, ks, lane), acc);
#pragma unroll
            for (int j = 0; j < 4; ++j) g_reg[rt][j] = silu_f(acc[j] * INV);
        }
    }

    // ---------------- phase 2: h1_i = (x1_i @ w1_v) * g -> overlay LDS ----------------
    {
        short8 bv[4];
#pragma unroll
        for (int ks = 0; ks < 4; ++ks) bv[ks] = wfrag<PACKED>(pw, w1v, 128, 16 + w, w, ks, lane);
#pragma unroll
        for (int i = 0; i < 3; ++i) {
            __syncthreads();  // i=0: X0 reads done; i>0: X1_{i-1} reads done
#pragma unroll
            for (int rt = 0; rt < 2; ++rt) {
                f32x4 acc = z;
#pragma unroll
                for (int ks = 0; ks < 4; ++ks)
                    acc = mfma16(bv[ks], lds_bfrag(sm, OFF_X1 + i * 8192, rt * 16, ks, lane), acc);
                short4v pkv;
#pragma unroll
                for (int j = 0; j < 4; ++j) pkv[j] = f2bf(acc[j] * INV * g_reg[rt][j]);
                int row = rt * 16 + (lane & 15);
                *(short4v*)(sm + i * 8192 + swz(row, 2 * (c0 + ((lane >> 4) << 2)))) = pkv;
            }
        }
    }
    __syncthreads();

    // ---------------- phase 3: y0 = h0 @ w2_s, y1_i = h1_i @ w2_v ----------------
    {
        short8 b2[4];
#pragma unroll
        for (int ks = 0; ks < 4; ++ks) b2[ks] = wfrag<PACKED>(pw, w2s, 128, 24 + w, w, ks, lane);
#pragma unroll
        for (int rt = 0; rt < 2; ++rt) {
            f32x4 acc = z;
#pragma unroll
            for (int ks = 0; ks < 4; ++ks)
                acc = mfma16(b2[ks], lds_bfrag(sm, OFF_H0, rt * 16, ks, lane), acc);
            int rg = row0g + rt * 16 + (lane & 15);
            if (rg < n) {
                float4 o = { acc[0] * INV, acc[1] * INV, acc[2] * INV, acc[3] * INV };
                *(float4*)(out + (size_t)rg * 512 + c0 + ((lane >> 4) << 2)) = o;
            }
        }
#pragma unroll
        for (int ks = 0; ks < 4; ++ks) b2[ks] = wfrag<PACKED>(pw, w2v, 128, 32 + w, w, ks, lane);
#pragma unroll
        for (int rt = 0; rt < 2; ++rt) {
            f32x4 a3[3];
#pragma unroll
            for (int i = 0; i < 3; ++i) {
                a3[i] = z;
#pragma unroll
                for (int ks = 0; ks < 4; ++ks)
                    a3[i] = mfma16(b2[ks], lds_bfrag(sm, i * 8192, rt * 16, ks, lane), a3[i]);
            }
            int rg = row0g + rt * 16 + (lane & 15);
            if (rg < n) {
                float* base = out + (size_t)rg * 512 + 128 + 3 * (c0 + ((lane >> 4) << 2));
                // element m (0..11): du=m/3, i=m%3, value a3[i][du]
                float4 s0 = { a3[0][0] * INV, a3[1][0] * INV, a3[2][0] * INV, a3[0][1] * INV };
                float4 s1 = { a3[1][1] * INV, a3[2][1] * INV, a3[0][2] * INV, a3[1][2] * INV };
                float4 s2 = { a3[2][2] * INV, a3[0][3] * INV, a3[1][3] * INV, a3[2][3] * INV };
                *(float4*)(base + 0) = s0;
                *(float4*)(base + 4) = s1;
                *(float4*)(base + 8) = s2;
            }
        }
    }
}

extern "C" void kernel_launch(void* const* d_in, const int* in_sizes, int n_in,
                              void* d_out, int out_size, void* d_ws, size_t ws_size,
                              hipStream_t stream) {
    const float* x   = (const float*)d_in[0];
    const float* w1s = (const float*)d_in[1];
    const float* w1v = (const float*)d_in[2];
    const float* w2s = (const float*)d_in[3];
    const float* w2v = (const float*)d_in[4];
    float* out = (float*)d_out;
    const int n = in_sizes[0] / 512;
    const int grid = (n + ROWS - 1) / ROWS;
    const size_t need = (size_t)40 * 4 * 64 * sizeof(short8);  // 163840 B
    if (ws_size >= need) {
        prep_pack<<<40, 256, 0, stream>>>(w1s, w1v, w2s, w2v, (short8*)d_ws);
        gnlr_fused_kernel<true><<<grid, TPB, 0, stream>>>(x, w1s, w1v, w2s, w2v,
                                                          (const short8*)d_ws, out, n);
    } else {
        gnlr_fused_kernel<false><<<grid, TPB, 0, stream>>>(x, w1s, w1v, w2s, w2v,
                                                           nullptr, out, n);
    }
}